// Round 2
// baseline (360.057 us; speedup 1.0000x reference)
//
#include <hip/hip_runtime.h>
#include <math.h>

#define BB   4
#define DD   128
#define LL   4096
#define SEG  64

union F4 { float4 v; float f[4]; };

__device__ __forceinline__ float gelu_f(float x){
  return 0.5f * x * (1.f + erff(x * 0.70710678118654752f));
}
__device__ __forceinline__ float softplus_f(float x){
  return (x > 20.f) ? x : log1pf(__expf(x));
}

// ---------------- K1: in_proj (1x1 conv 128->256), split, gelu(z) ----------------
__global__ __launch_bounds__(256) void k_inproj(const float* __restrict__ x,
    const float* __restrict__ W, float* __restrict__ xi, float* __restrict__ z1){
  __shared__ __align__(16) float Xs[128*64];
  int b = blockIdx.y; int p0 = blockIdx.x*64;
  int t = threadIdx.x;
  int po = t & 63, row4 = t >> 6;
  for (int j=0;j<32;j++){
    int c = row4 + 4*j;
    Xs[c*64 + po] = x[((size_t)(b*128 + c))*LL + p0 + po];
  }
  __syncthreads();
  int pg = t & 15, og = t >> 4;
  for (int j=0;j<4;j++){
    int obase = og*4 + j*64;
    const float4* w0r = (const float4*)&W[(size_t)(obase+0)*128];
    const float4* w1r = (const float4*)&W[(size_t)(obase+1)*128];
    const float4* w2r = (const float4*)&W[(size_t)(obase+2)*128];
    const float4* w3r = (const float4*)&W[(size_t)(obase+3)*128];
    float acc[4][4];
    #pragma unroll
    for (int i=0;i<4;i++) { acc[i][0]=0;acc[i][1]=0;acc[i][2]=0;acc[i][3]=0; }
    for (int c4=0;c4<32;c4++){
      F4 xv[4];
      #pragma unroll
      for (int r=0;r<4;r++) xv[r].v = *(const float4*)&Xs[(c4*4+r)*64 + pg*4];
      F4 wv[4];
      wv[0].v = w0r[c4]; wv[1].v = w1r[c4]; wv[2].v = w2r[c4]; wv[3].v = w3r[c4];
      #pragma unroll
      for (int i=0;i<4;i++)
        #pragma unroll
        for (int q=0;q<4;q++)
          acc[i][q] += wv[i].f[0]*xv[0].f[q] + wv[i].f[1]*xv[1].f[q]
                     + wv[i].f[2]*xv[2].f[q] + wv[i].f[3]*xv[3].f[q];
    }
    if (obase < 128){
      #pragma unroll
      for (int i=0;i<4;i++){
        F4 st; st.f[0]=acc[i][0]; st.f[1]=acc[i][1]; st.f[2]=acc[i][2]; st.f[3]=acc[i][3];
        *(float4*)&xi[((size_t)(b*128+obase+i))*LL + p0 + pg*4] = st.v;
      }
    } else {
      #pragma unroll
      for (int i=0;i<4;i++){
        F4 st; st.f[0]=gelu_f(acc[i][0]); st.f[1]=gelu_f(acc[i][1]);
        st.f[2]=gelu_f(acc[i][2]); st.f[3]=gelu_f(acc[i][3]);
        *(float4*)&z1[((size_t)(b*128+obase-128+i))*LL + p0 + pg*4] = st.v;
      }
    }
  }
}

// ---------------- K2: depthwise 3x3 + bias + gelu, channel mean/max pool ----------------
__global__ __launch_bounds__(256) void k_conv(const float* __restrict__ xi,
    const float* __restrict__ cw, const float* __restrict__ cb,
    float* __restrict__ xc, float* __restrict__ pooled){
  __shared__ float hs[4][10][12];
  __shared__ float redc[2][4][64];
  int b = blockIdx.z; int x0 = blockIdx.x*8, y0 = blockIdx.y*8;
  int t = threadIdx.x; int cz = t>>6; int pix = t&63; int py = pix>>3, px = pix&7;
  float msum = 0.f, mmax = -3.4e38f;
  for (int ci=0; ci<32; ci++){
    int c = cz*32 + ci;
    for (int e = pix; e < 100; e += 64){
      int ey = e/10, ex = e - ey*10;
      int gy = y0-1+ey, gx = x0-1+ex;
      float v = 0.f;
      if (gy>=0 && gy<64 && gx>=0 && gx<64)
        v = xi[((size_t)(b*128+c))*LL + gy*64+gx];
      hs[cz][ey][ex] = v;
    }
    __syncthreads();
    float a = 0.f;
    #pragma unroll
    for (int dy=0;dy<3;dy++)
      #pragma unroll
      for (int dx=0;dx<3;dx++)
        a += cw[c*9 + dy*3 + dx] * hs[cz][py+dy][px+dx];
    a += cb[c];
    a = gelu_f(a);
    xc[((size_t)(b*128+c))*LL + (y0+py)*64 + x0+px] = a;
    msum += a; mmax = fmaxf(mmax, a);
    __syncthreads();
  }
  redc[0][cz][pix] = msum; redc[1][cz][pix] = mmax;
  __syncthreads();
  if (t < 64){
    float s = redc[0][0][t]+redc[0][1][t]+redc[0][2][t]+redc[0][3][t];
    float mx = fmaxf(fmaxf(redc[1][0][t],redc[1][1][t]),fmaxf(redc[1][2][t],redc[1][3][t]));
    int p = (y0 + (t>>3))*64 + x0 + (t&7);
    pooled[((size_t)(b*2+0))*LL + p] = s*(1.f/128.f);
    pooled[((size_t)(b*2+1))*LL + p] = mx;
  }
}

// ---------------- K3: 7x7 conv (2ch->1) + sigmoid ----------------
__global__ __launch_bounds__(256) void k_attn(const float* __restrict__ pooled,
    const float* __restrict__ saw, const float* __restrict__ sab, float* __restrict__ sig){
  __shared__ float ps[2][10][70];
  int b = blockIdx.y; int p0 = blockIdx.x*256;
  int y0 = p0>>6;
  int t = threadIdx.x;
  for (int e=t; e<1400; e+=256){
    int ic = e/700; int rem = e - ic*700; int r = rem/70; int cc = rem - r*70;
    int gy = y0-3+r, gx = cc-3;
    float v = 0.f;
    if (gy>=0&&gy<64&&gx>=0&&gx<64) v = pooled[((size_t)(b*2+ic))*LL + gy*64+gx];
    ps[ic][r][cc] = v;
  }
  __syncthreads();
  int ry = t>>6, xx = t&63;
  float acc = sab[0];
  #pragma unroll
  for (int ic=0;ic<2;ic++)
    for (int ky=0;ky<7;ky++)
      #pragma unroll
      for (int kx=0;kx<7;kx++)
        acc += saw[ic*49+ky*7+kx] * ps[ic][ry+ky][xx+kx];
  sig[(size_t)b*LL + p0 + t] = 1.f/(1.f+__expf(-acc));
}

// ---------------- K4a: u = xc*sig (spatial) and transposed copy uT ----------------
__global__ __launch_bounds__(256) void k_gate(const float* __restrict__ xc,
    const float* __restrict__ sig, float* __restrict__ u, float* __restrict__ uT){
  __shared__ float tl[64*65];
  int d = blockIdx.x, b = blockIdx.y;
  const float* src = xc + ((size_t)(b*128+d))*LL;
  const float* sg  = sig + (size_t)b*LL;
  float* du = u  + ((size_t)(b*128+d))*LL;
  float* dT = uT + ((size_t)(b*128+d))*LL;
  int t = threadIdx.x;
  #pragma unroll
  for (int j=0;j<16;j++){
    int idx = t + j*256;
    int r = idx>>6, c = idx&63;
    float v = src[idx]*sg[idx];
    du[idx] = v;
    tl[c*65+r] = v;
  }
  __syncthreads();
  #pragma unroll
  for (int j=0;j<16;j++){
    int idx = t + j*256;
    int r = idx>>6, c = idx&63;
    dT[idx] = tl[r*65+c];
  }
}

// ---------------- K4b: x_dbl GEMM (40x128 @ 128xL) + dt proj + softplus, scan-order writes ----------------
__global__ __launch_bounds__(256) void k_xdbl(const float* __restrict__ u,
    const float* __restrict__ uT, const float* __restrict__ xpw,
    const float* __restrict__ dtw, const float* __restrict__ dtb,
    float* __restrict__ dt_l, float* __restrict__ Bs_l, float* __restrict__ Cs_l){
  int p  = blockIdx.x*256 + threadIdx.x;   // pixel (in this direction's order)
  int k  = blockIdx.y;
  int b  = blockIdx.z;
  int bk = b*4 + k;
  const float* ub = (k & 1) ? uT : u;
  const float* up = ub + ((size_t)b*128)*LL + p;
  const float* Wk = xpw + (size_t)k*40*128;

  float acc[40];
  #pragma unroll
  for (int r=0;r<40;r++) acc[r] = 0.f;

  for (int dc=0; dc<4; dc++){
    float uu[32];
    #pragma unroll
    for (int dd=0; dd<32; dd++) uu[dd] = up[(size_t)(dc*32+dd)*LL];
    #pragma unroll
    for (int r=0;r<40;r++){
      const float* wr = Wk + r*128 + dc*32;   // wave-uniform -> s_load
      float a = acc[r];
      #pragma unroll
      for (int dd=0; dd<32; dd++) a = fmaf(wr[dd], uu[dd], a);
      acc[r] = a;
    }
  }

  int lk = (k & 2) ? (LL-1-p) : p;

  // B rows 8..23, C rows 24..39
  {
    F4 st;
    #pragma unroll
    for (int q=0;q<4;q++){
      st.f[0]=acc[8+q*4+0]; st.f[1]=acc[8+q*4+1]; st.f[2]=acc[8+q*4+2]; st.f[3]=acc[8+q*4+3];
      *(float4*)&Bs_l[(((size_t)bk)*LL + lk)*16 + q*4] = st.v;
    }
    #pragma unroll
    for (int q=0;q<4;q++){
      st.f[0]=acc[24+q*4+0]; st.f[1]=acc[24+q*4+1]; st.f[2]=acc[24+q*4+2]; st.f[3]=acc[24+q*4+3];
      *(float4*)&Cs_l[(((size_t)bk)*LL + lk)*16 + q*4] = st.v;
    }
  }

  // dt: for each d, dot(dtw[k][d][:8], acc[0:8]) + dtb -> softplus
  const float* WD = dtw + (size_t)k*128*8;
  const float* BD = dtb + (size_t)k*128;
  float* dtp = dt_l + ((size_t)bk*128)*LL + lk;
  #pragma unroll 4
  for (int d=0; d<128; d++){
    const float* wd = WD + d*8;               // wave-uniform -> s_load
    float a = BD[d];
    #pragma unroll
    for (int r=0;r<8;r++) a = fmaf(wd[r], acc[r], a);
    dtp[(size_t)d*LL] = softplus_f(a);
  }
}

// ---------------- Scan phase 1: per-segment E (h from 0) and sum(dt) ----------------
__global__ __launch_bounds__(64) void k_scan1(const float* __restrict__ dt_l,
    const float* __restrict__ u, const float* __restrict__ uT,
    const float* __restrict__ Bs_l, const float* __restrict__ A_logs,
    float* __restrict__ Ebuf, float* __restrict__ sdtbuf){
  int seg = blockIdx.x, dh = blockIdx.y, bk = blockIdx.z;
  int b = bk>>2, k = bk&3;
  int lane = threadIdx.x; int d = dh*64 + lane;
  float A2[16];
  {
    const float4* al = (const float4*)&A_logs[((size_t)(k*128+d))*16];
    #pragma unroll
    for (int q=0;q<4;q++){
      F4 v; v.v = al[q];
      #pragma unroll
      for (int e=0;e<4;e++) A2[q*4+e] = -__expf(v.f[e]);
    }
  }
  float h[16];
  #pragma unroll
  for (int n=0;n<16;n++) h[n]=0.f;
  float sumdt = 0.f;
  const float* dtp  = dt_l + ((size_t)(bk*128 + d))*LL + seg*64;
  const float* ub   = (k & 1) ? uT : u;
  bool rev = (k >= 2);
  const float* up = rev ? (ub + ((size_t)(b*128+d))*LL + (LL-4 - seg*64))
                        : (ub + ((size_t)(b*128+d))*LL + seg*64);
  const float* Brow = Bs_l + (((size_t)bk)*LL + seg*64)*16;
  for (int i4=0;i4<16;i4++){
    F4 dtv; dtv.v = *(const float4*)(dtp + i4*4);
    F4 uv;
    if (!rev) uv.v = *(const float4*)(up + i4*4);
    else { F4 t0; t0.v = *(const float4*)(up - i4*4);
           uv.f[0]=t0.f[3]; uv.f[1]=t0.f[2]; uv.f[2]=t0.f[1]; uv.f[3]=t0.f[0]; }
    #pragma unroll
    for (int s=0;s<4;s++){
      float dt = dtv.f[s], uu = uv.f[s];
      const float* bp = Brow + (i4*4+s)*16;
      F4 b0,b1,b2,b3;
      b0.v = *(const float4*)(bp); b1.v = *(const float4*)(bp+4);
      b2.v = *(const float4*)(bp+8); b3.v = *(const float4*)(bp+12);
      float au = dt*uu;
      float bb[16];
      #pragma unroll
      for (int q=0;q<4;q++){ bb[q]=b0.f[q]; bb[4+q]=b1.f[q]; bb[8+q]=b2.f[q]; bb[12+q]=b3.f[q]; }
      #pragma unroll
      for (int n=0;n<16;n++) h[n] = __expf(dt*A2[n])*h[n] + au*bb[n];
      sumdt += dt;
    }
  }
  size_t eoff = ((size_t)(bk*128 + d))*SEG + seg;
  float* ep = Ebuf + eoff*16;
  #pragma unroll
  for (int q=0;q<4;q++){
    F4 st; st.f[0]=h[q*4+0]; st.f[1]=h[q*4+1]; st.f[2]=h[q*4+2]; st.f[3]=h[q*4+3];
    *(float4*)(ep + q*4) = st.v;
  }
  sdtbuf[eoff] = sumdt;
}

// ---------------- Scan phase 2: wave-parallel affine ladder scan over segments ----------------
// lane = segment; op: h' = a*h + e with a = exp(sumdt*A2[n]).
__global__ __launch_bounds__(64) void k_scan2(const float* __restrict__ Ebuf,
    const float* __restrict__ sdtbuf, const float* __restrict__ A_logs,
    float* __restrict__ hin){
  int d = blockIdx.x;     // 0..127
  int bk = blockIdx.y;    // 0..15
  int k = bk&3;
  int lane = threadIdx.x; // = seg
  size_t base = ((size_t)(bk*128+d))*SEG;
  float A2[16];
  {
    const float4* al = (const float4*)&A_logs[((size_t)(k*128+d))*16];
    #pragma unroll
    for (int q=0;q<4;q++){
      F4 v; v.v = al[q];
      #pragma unroll
      for (int e=0;e<4;e++) A2[q*4+e] = -__expf(v.f[e]);
    }
  }
  float sdt = sdtbuf[base + lane];
  float a[16], e[16];
  {
    const float* ep = Ebuf + (base+lane)*16;
    #pragma unroll
    for (int q=0;q<4;q++){
      F4 v; v.v = *(const float4*)(ep + q*4);
      #pragma unroll
      for (int ee=0;ee<4;ee++) e[q*4+ee]=v.f[ee];
    }
  }
  #pragma unroll
  for (int n=0;n<16;n++) a[n] = __expf(sdt*A2[n]);
  // inclusive Hillis-Steele scan over 64 lanes, composition (a2,e2)o(a1,e1) = (a1*a2, a2*e1+e2)
  #pragma unroll
  for (int off=1; off<64; off<<=1){
    #pragma unroll
    for (int n=0;n<16;n++){
      float pa = __shfl_up(a[n], off, 64);
      float pe = __shfl_up(e[n], off, 64);
      if (lane >= off){ e[n] = fmaf(a[n], pe, e[n]); a[n] *= pa; }
    }
  }
  // hin[seg] = inclusive-prefix e of seg-1 (h0 = 0)
  float* hp = hin + (base+lane)*16;
  #pragma unroll
  for (int q=0;q<4;q++){
    F4 st;
    #pragma unroll
    for (int ee=0;ee<4;ee++){
      float pe = __shfl_up(e[q*4+ee], 1, 64);
      st.f[ee] = (lane==0) ? 0.f : pe;
    }
    *(float4*)(hp + q*4) = st.v;
  }
}

// ---------------- Scan phase 3: replay with correct h_in, emit y ----------------
__global__ __launch_bounds__(64) void k_scan3(const float* __restrict__ dt_l,
    const float* __restrict__ u, const float* __restrict__ uT,
    const float* __restrict__ Bs_l, const float* __restrict__ Cs_l,
    const float* __restrict__ A_logs, const float* __restrict__ Ds,
    const float* __restrict__ hin, float* __restrict__ ys_l){
  int seg = blockIdx.x, dh = blockIdx.y, bk = blockIdx.z;
  int b = bk>>2, k = bk&3;
  int lane = threadIdx.x; int d = dh*64 + lane;
  float A2[16];
  {
    const float4* al = (const float4*)&A_logs[((size_t)(k*128+d))*16];
    #pragma unroll
    for (int q=0;q<4;q++){
      F4 v; v.v = al[q];
      #pragma unroll
      for (int e=0;e<4;e++) A2[q*4+e] = -__expf(v.f[e]);
    }
  }
  float h[16];
  {
    const float* hp = hin + (((size_t)(bk*128+d))*SEG + seg)*16;
    #pragma unroll
    for (int q=0;q<4;q++){
      F4 v; v.v = *(const float4*)(hp + q*4);
      #pragma unroll
      for (int e=0;e<4;e++) h[q*4+e]=v.f[e];
    }
  }
  float Dd = Ds[k*128+d];
  const float* dtp  = dt_l + ((size_t)(bk*128 + d))*LL + seg*64;
  const float* ub   = (k & 1) ? uT : u;
  bool rev = (k >= 2);
  const float* up = rev ? (ub + ((size_t)(b*128+d))*LL + (LL-4 - seg*64))
                        : (ub + ((size_t)(b*128+d))*LL + seg*64);
  const float* Brow = Bs_l + (((size_t)bk)*LL + seg*64)*16;
  const float* Crow = Cs_l + (((size_t)bk)*LL + seg*64)*16;
  float* yout = ys_l + ((size_t)(bk*128+d))*LL + seg*64;
  for (int i16=0;i16<4;i16++){
    float yreg[16];
    for (int i4=0;i4<4;i4++){
      int ii = i16*16 + i4*4;
      F4 dtv; dtv.v = *(const float4*)(dtp + ii);
      F4 uv;
      if (!rev) uv.v = *(const float4*)(up + ii);
      else { F4 t0; t0.v = *(const float4*)(up - ii);
             uv.f[0]=t0.f[3]; uv.f[1]=t0.f[2]; uv.f[2]=t0.f[1]; uv.f[3]=t0.f[0]; }
      #pragma unroll
      for (int s=0;s<4;s++){
        float dt = dtv.f[s], uu = uv.f[s];
        const float* bp = Brow + (ii+s)*16;
        const float* cp = Crow + (ii+s)*16;
        F4 b0,b1,b2,b3,c0,c1,c2,c3;
        b0.v = *(const float4*)(bp); b1.v = *(const float4*)(bp+4);
        b2.v = *(const float4*)(bp+8); b3.v = *(const float4*)(bp+12);
        c0.v = *(const float4*)(cp); c1.v = *(const float4*)(cp+4);
        c2.v = *(const float4*)(cp+8); c3.v = *(const float4*)(cp+12);
        float au = dt*uu;
        float bb[16], cc[16];
        #pragma unroll
        for (int q=0;q<4;q++){
          bb[q]=b0.f[q]; bb[4+q]=b1.f[q]; bb[8+q]=b2.f[q]; bb[12+q]=b3.f[q];
          cc[q]=c0.f[q]; cc[4+q]=c1.f[q]; cc[8+q]=c2.f[q]; cc[12+q]=c3.f[q];
        }
        float y = uu*Dd;
        #pragma unroll
        for (int n=0;n<16;n++){
          h[n] = __expf(dt*A2[n])*h[n] + au*bb[n];
          y = fmaf(h[n], cc[n], y);
        }
        yreg[i4*4+s] = y;
      }
    }
    #pragma unroll
    for (int q=0;q<4;q++){
      F4 st; st.f[0]=yreg[q*4+0]; st.f[1]=yreg[q*4+1]; st.f[2]=yreg[q*4+2]; st.f[3]=yreg[q*4+3];
      *(float4*)(yout + i16*16 + q*4) = st.v;
    }
  }
}

// ---------------- Merge 4 directions back to spatial order ----------------
__global__ __launch_bounds__(256) void k_merge(const float* __restrict__ ys_l,
    float* __restrict__ ysp){
  int b = blockIdx.z; int x0 = blockIdx.x*8, y0 = blockIdx.y*8;
  int t = threadIdx.x; int po = t&63; int dg = t>>6;
  int py = po>>3, px = po&7;
  int p  = (y0+py)*64 + x0+px;
  int pT = (x0+px)*64 + y0+py;
  for (int di=0; di<32; di++){
    int d = dg*32+di;
    float v = ys_l[((size_t)((b*4+0)*128+d))*LL + p]
            + ys_l[((size_t)((b*4+1)*128+d))*LL + pT]
            + ys_l[((size_t)((b*4+2)*128+d))*LL + (LL-1-p)]
            + ys_l[((size_t)((b*4+3)*128+d))*LL + (LL-1-pT)];
    ysp[((size_t)(b*128+d))*LL + p] = v;
  }
}

// ---------------- Final: LN(d) -> *z1 -> LN(d) -> out_proj ----------------
__global__ __launch_bounds__(256) void k_final(const float* __restrict__ ysp,
    const float* __restrict__ z1, const float* __restrict__ ong, const float* __restrict__ onb,
    const float* __restrict__ n1g, const float* __restrict__ n1b,
    const float* __restrict__ W2, float* __restrict__ out){
  __shared__ __align__(16) float yt[128*64];
  __shared__ float red[4][64], redq[4][64], mv[4][64];
  int b = blockIdx.y; int p0 = blockIdx.x*64;
  int t = threadIdx.x; int po = t&63; int rg = t>>6;
  float s=0.f, sq=0.f;
  for (int j=0;j<32;j++){
    int d = rg + 4*j;
    float v = ysp[((size_t)(b*128+d))*LL + p0 + po];
    yt[d*64+po] = v; s += v; sq += v*v;
  }
  red[rg][po] = s; redq[rg][po] = sq;
  __syncthreads();
  if (rg==0){
    float sm = red[0][po]+red[1][po]+red[2][po]+red[3][po];
    float qq = redq[0][po]+redq[1][po]+redq[2][po]+redq[3][po];
    float m = sm*(1.f/128.f);
    float var = qq*(1.f/128.f) - m*m;
    mv[0][po] = m; mv[1][po] = rsqrtf(var + 1e-5f);
  }
  __syncthreads();
  float m1 = mv[0][po], r1 = mv[1][po];
  s=0.f; sq=0.f;
  for (int j=0;j<32;j++){
    int d = rg + 4*j;
    float v = yt[d*64+po];
    float yn = (v-m1)*r1*ong[d] + onb[d];
    float tv = yn * z1[((size_t)(b*128+d))*LL + p0 + po];
    yt[d*64+po] = tv; s += tv; sq += tv*tv;
  }
  __syncthreads();
  red[rg][po] = s; redq[rg][po] = sq;
  __syncthreads();
  if (rg==0){
    float sm = red[0][po]+red[1][po]+red[2][po]+red[3][po];
    float qq = redq[0][po]+redq[1][po]+redq[2][po]+redq[3][po];
    float m = sm*(1.f/128.f);
    float var = qq*(1.f/128.f) - m*m;
    mv[2][po] = m; mv[3][po] = rsqrtf(var + 1e-6f);
  }
  __syncthreads();
  float m2 = mv[2][po], r2 = mv[3][po];
  for (int j=0;j<32;j++){
    int d = rg + 4*j;
    float tv = yt[d*64+po];
    yt[d*64+po] = (tv-m2)*r2*n1g[d] + n1b[d];
  }
  __syncthreads();
  int pg = t&15, og = t>>4;
  for (int j=0;j<2;j++){
    int obase = og*4 + j*64;
    const float4* w0r = (const float4*)&W2[(size_t)(obase+0)*128];
    const float4* w1r = (const float4*)&W2[(size_t)(obase+1)*128];
    const float4* w2r = (const float4*)&W2[(size_t)(obase+2)*128];
    const float4* w3r = (const float4*)&W2[(size_t)(obase+3)*128];
    float acc[4][4];
    #pragma unroll
    for (int i=0;i<4;i++){ acc[i][0]=0;acc[i][1]=0;acc[i][2]=0;acc[i][3]=0; }
    for (int c4=0;c4<32;c4++){
      F4 xv[4];
      #pragma unroll
      for (int r=0;r<4;r++) xv[r].v = *(const float4*)&yt[(c4*4+r)*64 + pg*4];
      F4 wv[4];
      wv[0].v = w0r[c4]; wv[1].v = w1r[c4]; wv[2].v = w2r[c4]; wv[3].v = w3r[c4];
      #pragma unroll
      for (int i=0;i<4;i++)
        #pragma unroll
        for (int q=0;q<4;q++)
          acc[i][q] += wv[i].f[0]*xv[0].f[q] + wv[i].f[1]*xv[1].f[q]
                     + wv[i].f[2]*xv[2].f[q] + wv[i].f[3]*xv[3].f[q];
    }
    #pragma unroll
    for (int i=0;i<4;i++){
      F4 st; st.f[0]=acc[i][0]; st.f[1]=acc[i][1]; st.f[2]=acc[i][2]; st.f[3]=acc[i][3];
      *(float4*)&out[((size_t)(b*128+obase+i))*LL + p0 + pg*4] = st.v;
    }
  }
}

extern "C" void kernel_launch(void* const* d_in, const int* in_sizes, int n_in,
                              void* d_out, int out_size, void* d_ws, size_t ws_size,
                              hipStream_t stream) {
  (void)in_sizes; (void)n_in; (void)out_size; (void)ws_size;
  const float* x    = (const float*)d_in[0];
  const float* ipw  = (const float*)d_in[1];
  const float* cw   = (const float*)d_in[2];
  const float* cb   = (const float*)d_in[3];
  const float* saw  = (const float*)d_in[4];
  const float* sab  = (const float*)d_in[5];
  const float* xpw  = (const float*)d_in[6];
  const float* dtw  = (const float*)d_in[7];
  const float* dtb  = (const float*)d_in[8];
  const float* alog = (const float*)d_in[9];
  const float* Dsv  = (const float*)d_in[10];
  const float* ong  = (const float*)d_in[11];
  const float* onb  = (const float*)d_in[12];
  const float* n1g  = (const float*)d_in[13];
  const float* n1b  = (const float*)d_in[14];
  const float* opw  = (const float*)d_in[15];

  float* ws = (float*)d_ws;
  const size_t SZ_BDL = (size_t)BB*128*LL;        // 2,097,152
  float* xi     = ws;
  float* z1     = xi  + SZ_BDL;
  float* xc     = z1  + SZ_BDL;
  float* pooled = xc  + SZ_BDL;                   // B*2*L
  float* sg     = pooled + (size_t)BB*2*LL;       // B*L
  float* u      = sg  + (size_t)BB*LL;
  float* uT     = u   + SZ_BDL;
  float* dt_l   = uT  + SZ_BDL;                   // B*4*128*L
  float* Bs_l   = dt_l+ (size_t)BB*4*128*LL;      // B*4*L*16
  float* Cs_l   = Bs_l+ (size_t)BB*4*LL*16;
  float* ys_l   = Cs_l+ (size_t)BB*4*LL*16;       // B*4*128*L
  float* ysp    = ys_l+ (size_t)BB*4*128*LL;
  float* Ebuf   = ysp + SZ_BDL;                   // B*4*128*SEG*16
  float* sdtb   = Ebuf+ (size_t)BB*4*128*SEG*16;  // B*4*128*SEG
  float* hin    = sdtb+ (size_t)BB*4*128*SEG;     // B*4*128*SEG*16

  k_inproj<<<dim3(64, BB), 256, 0, stream>>>(x, ipw, xi, z1);
  k_conv  <<<dim3(8, 8, BB), 256, 0, stream>>>(xi, cw, cb, xc, pooled);
  k_attn  <<<dim3(16, BB), 256, 0, stream>>>(pooled, saw, sab, sg);
  k_gate  <<<dim3(DD, BB), 256, 0, stream>>>(xc, sg, u, uT);
  k_xdbl  <<<dim3(16, 4, BB), 256, 0, stream>>>(u, uT, xpw, dtw, dtb, dt_l, Bs_l, Cs_l);
  k_scan1 <<<dim3(SEG, 2, BB*4), 64, 0, stream>>>(dt_l, u, uT, Bs_l, alog, Ebuf, sdtb);
  k_scan2 <<<dim3(128, BB*4), 64, 0, stream>>>(Ebuf, sdtb, alog, hin);
  k_scan3 <<<dim3(SEG, 2, BB*4), 64, 0, stream>>>(dt_l, u, uT, Bs_l, Cs_l, alog, Dsv, hin, ys_l);
  k_merge <<<dim3(8, 8, BB), 256, 0, stream>>>(ys_l, ysp);
  k_final <<<dim3(64, BB), 256, 0, stream>>>(ysp, z1, ong, onb, n1g, n1b, opw, (float*)d_out);
}

// Round 3
// 336.312 us; speedup vs baseline: 1.0706x; 1.0706x over previous
//
#include <hip/hip_runtime.h>
#include <math.h>

#define BB   4
#define DD   128
#define LL   4096
#define SEG  64

union F4 { float4 v; float f[4]; };

__device__ __forceinline__ float gelu_f(float x){
  return 0.5f * x * (1.f + erff(x * 0.70710678118654752f));
}
__device__ __forceinline__ float softplus_f(float x){
  return (x > 20.f) ? x : log1pf(__expf(x));
}

// ---------------- K1: in_proj (1x1 conv 128->256), split, gelu(z) ----------------
// blockIdx.y: half (0 -> xi rows 0..127, 1 -> z1 rows 128..255)
__global__ __launch_bounds__(256) void k_inproj(const float* __restrict__ x,
    const float* __restrict__ W, float* __restrict__ xi, float* __restrict__ z1){
  __shared__ __align__(16) float Xs[128*64];
  int b = blockIdx.z; int half = blockIdx.y; int p0 = blockIdx.x*64;
  int t = threadIdx.x;
  int po = t & 63, row4 = t >> 6;
  for (int j=0;j<32;j++){
    int c = row4 + 4*j;
    Xs[c*64 + po] = x[((size_t)(b*128 + c))*LL + p0 + po];
  }
  __syncthreads();
  int pg = t & 15, og = t >> 4;
  for (int j=0;j<2;j++){
    int obase = og*4 + j*64 + half*128;
    const float4* w0r = (const float4*)&W[(size_t)(obase+0)*128];
    const float4* w1r = (const float4*)&W[(size_t)(obase+1)*128];
    const float4* w2r = (const float4*)&W[(size_t)(obase+2)*128];
    const float4* w3r = (const float4*)&W[(size_t)(obase+3)*128];
    float acc[4][4];
    #pragma unroll
    for (int i=0;i<4;i++) { acc[i][0]=0;acc[i][1]=0;acc[i][2]=0;acc[i][3]=0; }
    for (int c4=0;c4<32;c4++){
      F4 xv[4];
      #pragma unroll
      for (int r=0;r<4;r++) xv[r].v = *(const float4*)&Xs[(c4*4+r)*64 + pg*4];
      F4 wv[4];
      wv[0].v = w0r[c4]; wv[1].v = w1r[c4]; wv[2].v = w2r[c4]; wv[3].v = w3r[c4];
      #pragma unroll
      for (int i=0;i<4;i++)
        #pragma unroll
        for (int q=0;q<4;q++)
          acc[i][q] += wv[i].f[0]*xv[0].f[q] + wv[i].f[1]*xv[1].f[q]
                     + wv[i].f[2]*xv[2].f[q] + wv[i].f[3]*xv[3].f[q];
    }
    if (half == 0){
      #pragma unroll
      for (int i=0;i<4;i++){
        F4 st; st.f[0]=acc[i][0]; st.f[1]=acc[i][1]; st.f[2]=acc[i][2]; st.f[3]=acc[i][3];
        *(float4*)&xi[((size_t)(b*128+obase+i))*LL + p0 + pg*4] = st.v;
      }
    } else {
      #pragma unroll
      for (int i=0;i<4;i++){
        F4 st; st.f[0]=gelu_f(acc[i][0]); st.f[1]=gelu_f(acc[i][1]);
        st.f[2]=gelu_f(acc[i][2]); st.f[3]=gelu_f(acc[i][3]);
        *(float4*)&z1[((size_t)(b*128+obase-128+i))*LL + p0 + pg*4] = st.v;
      }
    }
  }
}

// ---------------- K2: depthwise 3x3 + bias + gelu (grid-stride, no LDS) ----------------
__global__ __launch_bounds__(256) void k_conv(const float* __restrict__ xi,
    const float* __restrict__ cw, const float* __restrict__ cb, float* __restrict__ xc){
  int idx = blockIdx.x*256 + threadIdx.x;     // [b][c][p]
  int p = idx & 4095; int c = (idx>>12) & 127; int b = idx>>19;
  int y = p>>6, x = p&63;
  const float* src = xi + ((size_t)(b*128+c))*LL;
  float w[9];
  #pragma unroll
  for (int i=0;i<9;i++) w[i] = cw[c*9+i];     // c uniform per block -> scalar
  float a = cb[c];
  #pragma unroll
  for (int dy=-1;dy<=1;dy++){
    int yy = y+dy; if (yy<0 || yy>63) continue;
    #pragma unroll
    for (int dx=-1;dx<=1;dx++){
      int xx = x+dx; if (xx<0 || xx>63) continue;
      a = fmaf(w[(dy+1)*3+dx+1], src[yy*64+xx], a);
    }
  }
  xc[((size_t)(b*128+c))*LL + p] = gelu_f(a);
}

// ---------------- K2b: channel mean/max pool ----------------
__global__ __launch_bounds__(256) void k_pool(const float* __restrict__ xc,
    float* __restrict__ pooled){
  __shared__ float rs[4][64], rm[4][64];
  int b = blockIdx.y; int po = threadIdx.x & 63; int cg = threadIdx.x >> 6;
  int p = blockIdx.x*64 + po;
  const float* src = xc + ((size_t)b*128)*LL + p;
  float s = 0.f, mx = -3.4e38f;
  for (int ci=0;ci<32;ci++){
    float v = src[(size_t)(cg*32+ci)*LL];
    s += v; mx = fmaxf(mx, v);
  }
  rs[cg][po] = s; rm[cg][po] = mx;
  __syncthreads();
  if (cg == 0){
    float ss = rs[0][po]+rs[1][po]+rs[2][po]+rs[3][po];
    float mm = fmaxf(fmaxf(rm[0][po],rm[1][po]),fmaxf(rm[2][po],rm[3][po]));
    pooled[((size_t)(b*2+0))*LL + p] = ss*(1.f/128.f);
    pooled[((size_t)(b*2+1))*LL + p] = mm;
  }
}

// ---------------- K3: 7x7 conv (2ch->1) + sigmoid ----------------
__global__ __launch_bounds__(256) void k_attn(const float* __restrict__ pooled,
    const float* __restrict__ saw, const float* __restrict__ sab, float* __restrict__ sig){
  __shared__ float ps[2][10][70];
  int b = blockIdx.y; int p0 = blockIdx.x*256;
  int y0 = p0>>6;
  int t = threadIdx.x;
  for (int e=t; e<1400; e+=256){
    int ic = e/700; int rem = e - ic*700; int r = rem/70; int cc = rem - r*70;
    int gy = y0-3+r, gx = cc-3;
    float v = 0.f;
    if (gy>=0&&gy<64&&gx>=0&&gx<64) v = pooled[((size_t)(b*2+ic))*LL + gy*64+gx];
    ps[ic][r][cc] = v;
  }
  __syncthreads();
  int ry = t>>6, xx = t&63;
  float acc = sab[0];
  #pragma unroll
  for (int ic=0;ic<2;ic++)
    for (int ky=0;ky<7;ky++)
      #pragma unroll
      for (int kx=0;kx<7;kx++)
        acc += saw[ic*49+ky*7+kx] * ps[ic][ry+ky][xx+kx];
  sig[(size_t)b*LL + p0 + t] = 1.f/(1.f+__expf(-acc));
}

// ---------------- K4a: u = xc*sig (spatial) and transposed copy uT ----------------
__global__ __launch_bounds__(256) void k_gate(const float* __restrict__ xc,
    const float* __restrict__ sig, float* __restrict__ u, float* __restrict__ uT){
  __shared__ float tl[64*65];
  int d = blockIdx.x, b = blockIdx.y;
  const float* src = xc + ((size_t)(b*128+d))*LL;
  const float* sg  = sig + (size_t)b*LL;
  float* du = u  + ((size_t)(b*128+d))*LL;
  float* dT = uT + ((size_t)(b*128+d))*LL;
  int t = threadIdx.x;
  #pragma unroll
  for (int j=0;j<16;j++){
    int idx = t + j*256;
    int r = idx>>6, c = idx&63;
    float v = src[idx]*sg[idx];
    du[idx] = v;
    tl[c*65+r] = v;
  }
  __syncthreads();
  #pragma unroll
  for (int j=0;j<16;j++){
    int idx = t + j*256;
    int r = idx>>6, c = idx&63;
    dT[idx] = tl[r*65+c];
  }
}

// ---------------- K4pre: Wc[k][160][128]: rows 0..15 B, 16..31 C, 32..159 dtw@xpw_dt ----------------
__global__ __launch_bounds__(256) void k_wcomb(const float* __restrict__ xpw,
    const float* __restrict__ dtw, float* __restrict__ Wc){
  int k = blockIdx.x;
  const float* xp = xpw + (size_t)k*40*128;
  const float* dw = dtw + (size_t)k*128*8;
  float* W = Wc + (size_t)k*160*128;
  for (int idx = threadIdx.x; idx < 160*128; idx += 256){
    int row = idx >> 7, c = idx & 127;
    float v;
    if (row < 16)      v = xp[(8+row)*128 + c];
    else if (row < 32) v = xp[(8+row)*128 + c];     // 24+(row-16) == 8+row
    else {
      int d = row-32;
      v = 0.f;
      #pragma unroll
      for (int r=0;r<8;r++) v = fmaf(dw[d*8+r], xp[r*128+c], v);
    }
    W[idx] = v;
  }
}

// ---------------- K4b: fused 160x128 @ 128x64 tile-GEMM per (b,k,ptile) ----------------
// outputs: Bs_l/Cs_l n-major [bk][16][L], dt_l [bk][128][L] (softplus applied), scan order.
__global__ __launch_bounds__(256) void k_xdbl(const float* __restrict__ u,
    const float* __restrict__ uT, const float* __restrict__ Wc,
    const float* __restrict__ dtb,
    float* __restrict__ dt_l, float* __restrict__ Bs_l, float* __restrict__ Cs_l){
  __shared__ __align__(16) float Xs[128*64];
  int p0 = blockIdx.x*64; int k = blockIdx.y; int b = blockIdx.z; int bk = b*4+k;
  int t = threadIdx.x;
  const float* ub = (k&1) ? uT : u;
  int po = t&63, row4 = t>>6;
  for (int j=0;j<32;j++){
    int c = row4 + 4*j;
    Xs[c*64+po] = ub[((size_t)(b*128+c))*LL + p0 + po];
  }
  __syncthreads();
  int pg = t&15, og = t>>4;
  const float* Wk = Wc + (size_t)k*160*128;
  int pp = p0 + pg*4;
  for (int j=0;j<3;j++){
    int rbase = j*64 + og*4;
    if (rbase < 160){
      const float4* w0r = (const float4*)&Wk[(size_t)(rbase+0)*128];
      const float4* w1r = (const float4*)&Wk[(size_t)(rbase+1)*128];
      const float4* w2r = (const float4*)&Wk[(size_t)(rbase+2)*128];
      const float4* w3r = (const float4*)&Wk[(size_t)(rbase+3)*128];
      float acc[4][4];
      #pragma unroll
      for (int i=0;i<4;i++){ acc[i][0]=0;acc[i][1]=0;acc[i][2]=0;acc[i][3]=0; }
      for (int c4=0;c4<32;c4++){
        F4 xv[4];
        #pragma unroll
        for (int r=0;r<4;r++) xv[r].v = *(const float4*)&Xs[(c4*4+r)*64 + pg*4];
        F4 wv[4];
        wv[0].v = w0r[c4]; wv[1].v = w1r[c4]; wv[2].v = w2r[c4]; wv[3].v = w3r[c4];
        #pragma unroll
        for (int i=0;i<4;i++)
          #pragma unroll
          for (int q=0;q<4;q++)
            acc[i][q] += wv[i].f[0]*xv[0].f[q] + wv[i].f[1]*xv[1].f[q]
                       + wv[i].f[2]*xv[2].f[q] + wv[i].f[3]*xv[3].f[q];
      }
      #pragma unroll
      for (int i=0;i<4;i++){
        int rr = rbase + i;
        float v0=acc[i][0], v1=acc[i][1], v2=acc[i][2], v3=acc[i][3];
        float* dst;
        if (rr < 16)       dst = Bs_l + ((size_t)(bk*16 + rr))*LL;
        else if (rr < 32)  dst = Cs_l + ((size_t)(bk*16 + rr-16))*LL;
        else {
          int d = rr - 32;
          float bias = dtb[k*128+d];
          v0 = softplus_f(v0+bias); v1 = softplus_f(v1+bias);
          v2 = softplus_f(v2+bias); v3 = softplus_f(v3+bias);
          dst = dt_l + ((size_t)(bk*128 + d))*LL;
        }
        F4 st;
        if (k < 2){
          st.f[0]=v0; st.f[1]=v1; st.f[2]=v2; st.f[3]=v3;
          *(float4*)&dst[pp] = st.v;
        } else {
          st.f[0]=v3; st.f[1]=v2; st.f[2]=v1; st.f[3]=v0;
          *(float4*)&dst[LL-4-pp] = st.v;
        }
      }
    }
  }
}

// ---------------- Scan phase 1: per-segment E (h from 0) and sum(dt) ----------------
__global__ __launch_bounds__(64) void k_scan1(const float* __restrict__ dt_l,
    const float* __restrict__ u, const float* __restrict__ uT,
    const float* __restrict__ Bs_l, const float* __restrict__ A_logs,
    float* __restrict__ Ebuf, float* __restrict__ sdtbuf){
  int seg = blockIdx.x, dh = blockIdx.y, bk = blockIdx.z;
  int b = bk>>2, k = bk&3;
  int lane = threadIdx.x; int d = dh*64 + lane;
  float A2[16];
  {
    const float4* al = (const float4*)&A_logs[((size_t)(k*128+d))*16];
    #pragma unroll
    for (int q=0;q<4;q++){
      F4 v; v.v = al[q];
      #pragma unroll
      for (int e=0;e<4;e++) A2[q*4+e] = -__expf(v.f[e]);
    }
  }
  float h[16];
  #pragma unroll
  for (int n=0;n<16;n++) h[n]=0.f;
  float sumdt = 0.f;
  const float* dtp  = dt_l + ((size_t)(bk*128 + d))*LL + seg*64;
  const float* ub   = (k & 1) ? uT : u;
  bool rev = (k >= 2);
  const float* up = rev ? (ub + ((size_t)(b*128+d))*LL + (LL-4 - seg*64))
                        : (ub + ((size_t)(b*128+d))*LL + seg*64);
  const float* Bn = Bs_l + ((size_t)bk*16)*LL + seg*64;
  for (int i4=0;i4<16;i4++){
    F4 dtv; dtv.v = *(const float4*)(dtp + i4*4);
    F4 uv;
    if (!rev) uv.v = *(const float4*)(up + i4*4);
    else { F4 t0; t0.v = *(const float4*)(up - i4*4);
           uv.f[0]=t0.f[3]; uv.f[1]=t0.f[2]; uv.f[2]=t0.f[1]; uv.f[3]=t0.f[0]; }
    F4 Bq[16];
    #pragma unroll
    for (int n=0;n<16;n++) Bq[n].v = *(const float4*)(Bn + (size_t)n*LL + i4*4);
    #pragma unroll
    for (int s=0;s<4;s++){
      float dt = dtv.f[s], uu = uv.f[s];
      float au = dt*uu;
      #pragma unroll
      for (int n=0;n<16;n++) h[n] = __expf(dt*A2[n])*h[n] + au*Bq[n].f[s];
      sumdt += dt;
    }
  }
  size_t eoff = ((size_t)(bk*128 + d))*SEG + seg;
  float* ep = Ebuf + eoff*16;
  #pragma unroll
  for (int q=0;q<4;q++){
    F4 st; st.f[0]=h[q*4+0]; st.f[1]=h[q*4+1]; st.f[2]=h[q*4+2]; st.f[3]=h[q*4+3];
    *(float4*)(ep + q*4) = st.v;
  }
  sdtbuf[eoff] = sumdt;
}

// ---------------- Scan phase 2: wave-parallel affine ladder scan over segments ----------------
__global__ __launch_bounds__(64) void k_scan2(const float* __restrict__ Ebuf,
    const float* __restrict__ sdtbuf, const float* __restrict__ A_logs,
    float* __restrict__ hin){
  int d = blockIdx.x;
  int bk = blockIdx.y;
  int k = bk&3;
  int lane = threadIdx.x; // = seg
  size_t base = ((size_t)(bk*128+d))*SEG;
  float A2[16];
  {
    const float4* al = (const float4*)&A_logs[((size_t)(k*128+d))*16];
    #pragma unroll
    for (int q=0;q<4;q++){
      F4 v; v.v = al[q];
      #pragma unroll
      for (int e=0;e<4;e++) A2[q*4+e] = -__expf(v.f[e]);
    }
  }
  float sdt = sdtbuf[base + lane];
  float a[16], e[16];
  {
    const float* ep = Ebuf + (base+lane)*16;
    #pragma unroll
    for (int q=0;q<4;q++){
      F4 v; v.v = *(const float4*)(ep + q*4);
      #pragma unroll
      for (int ee=0;ee<4;ee++) e[q*4+ee]=v.f[ee];
    }
  }
  #pragma unroll
  for (int n=0;n<16;n++) a[n] = __expf(sdt*A2[n]);
  #pragma unroll
  for (int off=1; off<64; off<<=1){
    #pragma unroll
    for (int n=0;n<16;n++){
      float pa = __shfl_up(a[n], off, 64);
      float pe = __shfl_up(e[n], off, 64);
      if (lane >= off){ e[n] = fmaf(a[n], pe, e[n]); a[n] *= pa; }
    }
  }
  float* hp = hin + (base+lane)*16;
  #pragma unroll
  for (int q=0;q<4;q++){
    F4 st;
    #pragma unroll
    for (int ee=0;ee<4;ee++){
      float pe = __shfl_up(e[q*4+ee], 1, 64);
      st.f[ee] = (lane==0) ? 0.f : pe;
    }
    *(float4*)(hp + q*4) = st.v;
  }
}

// ---------------- Scan phase 3: replay with correct h_in, emit y ----------------
__global__ __launch_bounds__(64) void k_scan3(const float* __restrict__ dt_l,
    const float* __restrict__ u, const float* __restrict__ uT,
    const float* __restrict__ Bs_l, const float* __restrict__ Cs_l,
    const float* __restrict__ A_logs, const float* __restrict__ Ds,
    const float* __restrict__ hin, float* __restrict__ ys_l){
  int seg = blockIdx.x, dh = blockIdx.y, bk = blockIdx.z;
  int b = bk>>2, k = bk&3;
  int lane = threadIdx.x; int d = dh*64 + lane;
  float A2[16];
  {
    const float4* al = (const float4*)&A_logs[((size_t)(k*128+d))*16];
    #pragma unroll
    for (int q=0;q<4;q++){
      F4 v; v.v = al[q];
      #pragma unroll
      for (int e=0;e<4;e++) A2[q*4+e] = -__expf(v.f[e]);
    }
  }
  float h[16];
  {
    const float* hp = hin + (((size_t)(bk*128+d))*SEG + seg)*16;
    #pragma unroll
    for (int q=0;q<4;q++){
      F4 v; v.v = *(const float4*)(hp + q*4);
      #pragma unroll
      for (int e=0;e<4;e++) h[q*4+e]=v.f[e];
    }
  }
  float Dd = Ds[k*128+d];
  const float* dtp  = dt_l + ((size_t)(bk*128 + d))*LL + seg*64;
  const float* ub   = (k & 1) ? uT : u;
  bool rev = (k >= 2);
  const float* up = rev ? (ub + ((size_t)(b*128+d))*LL + (LL-4 - seg*64))
                        : (ub + ((size_t)(b*128+d))*LL + seg*64);
  const float* Bn = Bs_l + ((size_t)bk*16)*LL + seg*64;
  const float* Cn = Cs_l + ((size_t)bk*16)*LL + seg*64;
  float* yout = ys_l + ((size_t)(bk*128+d))*LL + seg*64;
  for (int i4=0;i4<16;i4++){
    F4 dtv; dtv.v = *(const float4*)(dtp + i4*4);
    F4 uv;
    if (!rev) uv.v = *(const float4*)(up + i4*4);
    else { F4 t0; t0.v = *(const float4*)(up - i4*4);
           uv.f[0]=t0.f[3]; uv.f[1]=t0.f[2]; uv.f[2]=t0.f[1]; uv.f[3]=t0.f[0]; }
    F4 Bq[16], Cq[16];
    #pragma unroll
    for (int n=0;n<16;n++){
      Bq[n].v = *(const float4*)(Bn + (size_t)n*LL + i4*4);
      Cq[n].v = *(const float4*)(Cn + (size_t)n*LL + i4*4);
    }
    F4 yv;
    #pragma unroll
    for (int s=0;s<4;s++){
      float dt = dtv.f[s], uu = uv.f[s];
      float au = dt*uu;
      float y = uu*Dd;
      #pragma unroll
      for (int n=0;n<16;n++){
        h[n] = __expf(dt*A2[n])*h[n] + au*Bq[n].f[s];
        y = fmaf(h[n], Cq[n].f[s], y);
      }
      yv.f[s] = y;
    }
    *(float4*)(yout + i4*4) = yv.v;
  }
}

// ---------------- Merge 4 directions back to spatial order (LDS transpose) ----------------
__global__ __launch_bounds__(256) void k_merge(const float* __restrict__ ys_l,
    float* __restrict__ ysp){
  __shared__ float t1[64*65];
  __shared__ float t3[64*65];
  int d = blockIdx.x, b = blockIdx.y;
  const float* y0p = ys_l + ((size_t)((b*4+0)*128+d))*LL;
  const float* y1p = ys_l + ((size_t)((b*4+1)*128+d))*LL;
  const float* y2p = ys_l + ((size_t)((b*4+2)*128+d))*LL;
  const float* y3p = ys_l + ((size_t)((b*4+3)*128+d))*LL;
  float* op = ysp + ((size_t)(b*128+d))*LL;
  int t = threadIdx.x;
  #pragma unroll
  for (int j=0;j<16;j++){
    int q = t + j*256;
    int xq = q>>6, yq = q&63;       // q = xq*64 + yq
    t1[xq*65+yq] = y1p[q];
    t3[xq*65+yq] = y3p[q];
  }
  __syncthreads();
  #pragma unroll
  for (int j=0;j<16;j++){
    int p = t + j*256;
    int y = p>>6, x = p&63;         // p = y*64 + x; q(p) = x*64 + y
    float v = y0p[p] + y2p[LL-1-p]
            + t1[x*65+y] + t3[(63-x)*65 + (63-y)];
    op[p] = v;
  }
}

// ---------------- Final: LN(d) -> *z1 -> LN(d) -> out_proj ----------------
__global__ __launch_bounds__(256) void k_final(const float* __restrict__ ysp,
    const float* __restrict__ z1, const float* __restrict__ ong, const float* __restrict__ onb,
    const float* __restrict__ n1g, const float* __restrict__ n1b,
    const float* __restrict__ W2, float* __restrict__ out){
  __shared__ __align__(16) float yt[128*64];
  __shared__ float red[4][64], redq[4][64], mv[4][64];
  int b = blockIdx.y; int p0 = blockIdx.x*64;
  int t = threadIdx.x; int po = t&63; int rg = t>>6;
  float s=0.f, sq=0.f;
  for (int j=0;j<32;j++){
    int d = rg + 4*j;
    float v = ysp[((size_t)(b*128+d))*LL + p0 + po];
    yt[d*64+po] = v; s += v; sq += v*v;
  }
  red[rg][po] = s; redq[rg][po] = sq;
  __syncthreads();
  if (rg==0){
    float sm = red[0][po]+red[1][po]+red[2][po]+red[3][po];
    float qq = redq[0][po]+redq[1][po]+redq[2][po]+redq[3][po];
    float m = sm*(1.f/128.f);
    float var = qq*(1.f/128.f) - m*m;
    mv[0][po] = m; mv[1][po] = rsqrtf(var + 1e-5f);
  }
  __syncthreads();
  float m1 = mv[0][po], r1 = mv[1][po];
  s=0.f; sq=0.f;
  for (int j=0;j<32;j++){
    int d = rg + 4*j;
    float v = yt[d*64+po];
    float yn = (v-m1)*r1*ong[d] + onb[d];
    float tv = yn * z1[((size_t)(b*128+d))*LL + p0 + po];
    yt[d*64+po] = tv; s += tv; sq += tv*tv;
  }
  __syncthreads();
  red[rg][po] = s; redq[rg][po] = sq;
  __syncthreads();
  if (rg==0){
    float sm = red[0][po]+red[1][po]+red[2][po]+red[3][po];
    float qq = redq[0][po]+redq[1][po]+redq[2][po]+redq[3][po];
    float m = sm*(1.f/128.f);
    float var = qq*(1.f/128.f) - m*m;
    mv[2][po] = m; mv[3][po] = rsqrtf(var + 1e-6f);
  }
  __syncthreads();
  float m2 = mv[2][po], r2 = mv[3][po];
  for (int j=0;j<32;j++){
    int d = rg + 4*j;
    float tv = yt[d*64+po];
    yt[d*64+po] = (tv-m2)*r2*n1g[d] + n1b[d];
  }
  __syncthreads();
  int pg = t&15, og = t>>4;
  for (int j=0;j<2;j++){
    int obase = og*4 + j*64;
    const float4* w0r = (const float4*)&W2[(size_t)(obase+0)*128];
    const float4* w1r = (const float4*)&W2[(size_t)(obase+1)*128];
    const float4* w2r = (const float4*)&W2[(size_t)(obase+2)*128];
    const float4* w3r = (const float4*)&W2[(size_t)(obase+3)*128];
    float acc[4][4];
    #pragma unroll
    for (int i=0;i<4;i++){ acc[i][0]=0;acc[i][1]=0;acc[i][2]=0;acc[i][3]=0; }
    for (int c4=0;c4<32;c4++){
      F4 xv[4];
      #pragma unroll
      for (int r=0;r<4;r++) xv[r].v = *(const float4*)&yt[(c4*4+r)*64 + pg*4];
      F4 wv[4];
      wv[0].v = w0r[c4]; wv[1].v = w1r[c4]; wv[2].v = w2r[c4]; wv[3].v = w3r[c4];
      #pragma unroll
      for (int i=0;i<4;i++)
        #pragma unroll
        for (int q=0;q<4;q++)
          acc[i][q] += wv[i].f[0]*xv[0].f[q] + wv[i].f[1]*xv[1].f[q]
                     + wv[i].f[2]*xv[2].f[q] + wv[i].f[3]*xv[3].f[q];
    }
    #pragma unroll
    for (int i=0;i<4;i++){
      F4 st; st.f[0]=acc[i][0]; st.f[1]=acc[i][1]; st.f[2]=acc[i][2]; st.f[3]=acc[i][3];
      *(float4*)&out[((size_t)(b*128+obase+i))*LL + p0 + pg*4] = st.v;
    }
  }
}

extern "C" void kernel_launch(void* const* d_in, const int* in_sizes, int n_in,
                              void* d_out, int out_size, void* d_ws, size_t ws_size,
                              hipStream_t stream) {
  (void)in_sizes; (void)n_in; (void)out_size; (void)ws_size;
  const float* x    = (const float*)d_in[0];
  const float* ipw  = (const float*)d_in[1];
  const float* cw   = (const float*)d_in[2];
  const float* cb   = (const float*)d_in[3];
  const float* saw  = (const float*)d_in[4];
  const float* sab  = (const float*)d_in[5];
  const float* xpw  = (const float*)d_in[6];
  const float* dtw  = (const float*)d_in[7];
  const float* dtb  = (const float*)d_in[8];
  const float* alog = (const float*)d_in[9];
  const float* Dsv  = (const float*)d_in[10];
  const float* ong  = (const float*)d_in[11];
  const float* onb  = (const float*)d_in[12];
  const float* n1g  = (const float*)d_in[13];
  const float* n1b  = (const float*)d_in[14];
  const float* opw  = (const float*)d_in[15];

  float* ws = (float*)d_ws;
  const size_t SZ_BDL = (size_t)BB*128*LL;
  float* xi     = ws;
  float* z1     = xi  + SZ_BDL;
  float* xc     = z1  + SZ_BDL;
  float* pooled = xc  + SZ_BDL;
  float* sg     = pooled + (size_t)BB*2*LL;
  float* u      = sg  + (size_t)BB*LL;
  float* uT     = u   + SZ_BDL;
  float* dt_l   = uT  + SZ_BDL;
  float* Bs_l   = dt_l+ (size_t)BB*4*128*LL;
  float* Cs_l   = Bs_l+ (size_t)BB*4*16*LL;
  float* ys_l   = Cs_l+ (size_t)BB*4*16*LL;
  float* ysp    = ys_l+ (size_t)BB*4*128*LL;
  float* Ebuf   = ysp + SZ_BDL;
  float* sdtb   = Ebuf+ (size_t)BB*4*128*SEG*16;
  float* hin    = sdtb+ (size_t)BB*4*128*SEG;
  float* Wc     = hin + (size_t)BB*4*128*SEG*16;   // 4*160*128

  k_wcomb <<<dim3(4), 256, 0, stream>>>(xpw, dtw, Wc);
  k_inproj<<<dim3(64, 2, BB), 256, 0, stream>>>(x, ipw, xi, z1);
  k_conv  <<<dim3(BB*128*LL/256), 256, 0, stream>>>(xi, cw, cb, xc);
  k_pool  <<<dim3(64, BB), 256, 0, stream>>>(xc, pooled);
  k_attn  <<<dim3(16, BB), 256, 0, stream>>>(pooled, saw, sab, sg);
  k_gate  <<<dim3(DD, BB), 256, 0, stream>>>(xc, sg, u, uT);
  k_xdbl  <<<dim3(64, 4, BB), 256, 0, stream>>>(u, uT, Wc, dtb, dt_l, Bs_l, Cs_l);
  k_scan1 <<<dim3(SEG, 2, BB*4), 64, 0, stream>>>(dt_l, u, uT, Bs_l, alog, Ebuf, sdtb);
  k_scan2 <<<dim3(128, BB*4), 64, 0, stream>>>(Ebuf, sdtb, alog, hin);
  k_scan3 <<<dim3(SEG, 2, BB*4), 64, 0, stream>>>(dt_l, u, uT, Bs_l, Cs_l, alog, Dsv, hin, ys_l);
  k_merge <<<dim3(DD, BB), 256, 0, stream>>>(ys_l, ysp);
  k_final <<<dim3(64, BB), 256, 0, stream>>>(ysp, z1, ong, onb, n1g, n1b, opw, (float*)d_out);
}